// Round 20
// baseline (829.575 us; speedup 1.0000x reference)
//
#include <hip/hip_runtime.h>
#include <hip/hip_bf16.h>

// LSTMReg on MI355X — round 20: r19 + FUSED x CONVERSION (prepass deleted).
// r19 (788us) = 45us serialized xconv prepass + ~743us latency-bound fused
// loop (MfmaUtil 28 / VALUBusy 28 / no pipe saturated). This round: L0 waves
// load raw fp32 x directly (4x float4/lane/step, 16x column-duplicated ->
// L2 broadcast) and convert in-register with RNE v_cvt (bit-identical to
// xconv's output) during phase B where 6/8 L0 waves idle. Loads issued one
// full iteration (~1590 cyc) ahead of conversion -> covers HBM latency.
// Schedule/maps/arithmetic = r19 verbatim -> absmax exactly 2.441406e-4.

typedef _Float16 f16x8 __attribute__((ext_vector_type(8)));
typedef float f32x4  __attribute__((ext_vector_type(4)));

#define MFMAH(A, B, C) __builtin_amdgcn_mfma_f32_16x16x32_f16(A, B, C, 0, 0, 0)

constexpr int T_LEN = 1024;
constexpr int H     = 64;
constexpr int NCH   = 2;     // chains per block -> 256 blocks = all CUs
constexpr int NTHR  = 1024;  // 16 waves = 4/SIMD
constexpr int NBLK  = 256;

__device__ __forceinline__ float sigm_f(float x) {
  return __builtin_amdgcn_rcpf(1.0f + __expf(-x));
}
__device__ __forceinline__ float tanh_f(float x) {
  return 1.0f - 2.0f * __builtin_amdgcn_rcpf(1.0f + __expf(2.0f * x));
}
__device__ __forceinline__ unsigned dpp_xor1_u32(unsigned v) {
  return (unsigned)__builtin_amdgcn_mov_dpp((int)v, 0xB1, 0xF, 0xF, true);
}
// LDS-only barrier (keeps global x loads in flight across barriers)
__device__ __forceinline__ void lds_barrier() {
  asm volatile("s_waitcnt lgkmcnt(0)" ::: "memory");
  __builtin_amdgcn_s_barrier();
  asm volatile("" ::: "memory");
}
// 8x fp32 -> f16x8 (RNE v_cvt_f16_f32; identical to old xconv packing)
__device__ __forceinline__ f16x8 cvt8(float4 u, float4 v) {
  f16x8 r;
  r[0] = (_Float16)u.x; r[1] = (_Float16)u.y;
  r[2] = (_Float16)u.z; r[3] = (_Float16)u.w;
  r[4] = (_Float16)v.x; r[5] = (_Float16)v.y;
  r[6] = (_Float16)v.z; r[7] = (_Float16)v.w;
  return r;
}

__global__ __launch_bounds__(NTHR) void lstm_fused(
    const float* __restrict__ xin,
    const float* __restrict__ w_ih0, const float* __restrict__ w_hh0,
    const float* __restrict__ b_ih0, const float* __restrict__ b_hh0,
    const float* __restrict__ w_ih1, const float* __restrict__ w_hh1,
    const float* __restrict__ b_ih1, const float* __restrict__ b_hh1,
    const float* __restrict__ fc_w, const float* __restrict__ fc_b,
    float* __restrict__ out) {
  const int tid = threadIdx.x;
  const int wv  = tid >> 6;
  const int L   = wv >> 3;   // 0: L0 waves (wv0-7), 1: L1 waves (wv8-15)
  const int w8  = wv & 7;    // row-block: rows [32*w8, 32*w8+32)
  const int l   = tid & 63;
  const int col = l & 15;    // MFMA column; chain = col&1 (8x duplicated)
  const int lq  = l >> 4;
  const int blk = blockIdx.x;

  // h buffers: [layer][buf][kt(2)][lq(4)][ch(2)][e(8)] = 128 halfs per buf
  __shared__ __align__(16) _Float16 hb[2][2][128];
  __shared__ __align__(16) float zp[2][2][260];   // [L][chain][row(+pad)]
  __shared__ float bias_s[2][256];
  __shared__ float fcw_s[H];
  __shared__ float hfin[NCH][H];

  for (int i = tid; i < 2 * 2 * 128; i += NTHR) ((_Float16*)hb)[i] = (_Float16)0.f;
  if (tid < 256)       bias_s[0][tid] = b_ih0[tid] + b_hh0[tid];
  else if (tid < 512)  bias_s[1][tid - 256] = b_ih1[tid - 256] + b_hh1[tid - 256];
  if (tid < H) fcw_s[tid] = fc_w[tid];

  // ---- weights: rows 32*w8 + 16*rt + col; k0 = 32kt + 8lq (= r19 map) ----
  const float* wih = L ? w_ih1 : w_ih0;
  const float* whh = L ? w_hh1 : w_hh0;
  f16x8 w16[2][4];  // [rt][kt] = 32 VGPR
#pragma unroll
  for (int rt = 0; rt < 2; ++rt) {
#pragma unroll
    for (int kt = 0; kt < 4; ++kt) {
      const int row = 32 * w8 + 16 * rt + col;
      const int k0  = 32 * kt + 8 * lq;
      const float* src = (k0 < 64) ? &wih[row * 64 + k0] : &whh[row * 64 + (k0 - 64)];
      float4 v0 = *reinterpret_cast<const float4*>(src);
      float4 v1 = *reinterpret_cast<const float4*>(src + 4);
      float vv[8] = {v0.x, v0.y, v0.z, v0.w, v1.x, v1.y, v1.z, v1.w};
      f16x8 h8;
#pragma unroll
      for (int e = 0; e < 8; ++e) h8[e] = (_Float16)vv[e];
      w16[rt][kt] = h8;
    }
  }

  // B-frag LDS read offset (halfs): lq*16 + (col&1)*8  (+64 for kt1)
  const int rdoff = lq * 16 + (col & 1) * 8;
  // gate waves: wv0(S0),wv1(S1) for L0; wv10(S2),wv11(S3) for L1
  const bool is_gate = (wv < 2) || (wv == 10) || (wv == 11);
  const int gch = wv & 1;    // chain
  const int gh  = l;         // feature
  // h write addr (halfs): f=gh -> kt=gh>>5, lq=(gh>>3)&3, e=gh&7
  const int waddr_h = ((gh >> 5) << 6) + (((gh >> 3) & 3) << 4) + (gch << 3) + (gh & 7);
  float cst = 0.0f;

  // ---- x pipeline (L0 waves): raw fp32 loads + in-reg RNE conversion ----
  // lane reads chain blk*2 + (col&1), feats 8lq..+8 (kt0) and 32+8lq..+8 (kt1)
  const float* xp = xin + ((size_t)(blk * NCH + (col & 1)) * T_LEN) * H + 8 * lq;
  f16x8 xb0, xb1, xbn0, xbn1;
  float4 xr0, xr1, xr2, xr3;   // raw fp32 for step t+1 (in flight/held)
  if (L == 0) {
    float4 a0_ = *reinterpret_cast<const float4*>(xp);
    float4 a1_ = *reinterpret_cast<const float4*>(xp + 4);
    float4 a2_ = *reinterpret_cast<const float4*>(xp + 32);
    float4 a3_ = *reinterpret_cast<const float4*>(xp + 36);
    xb0 = cvt8(a0_, a1_);   // t = 0, kt0
    xb1 = cvt8(a2_, a3_);   // t = 0, kt1
    const float* p = xp + H;  // t = 1
    xr0 = *reinterpret_cast<const float4*>(p);
    xr1 = *reinterpret_cast<const float4*>(p + 4);
    xr2 = *reinterpret_cast<const float4*>(p + 32);
    xr3 = *reinterpret_cast<const float4*>(p + 36);
  }

  const f32x4 zf4 = {0.f, 0.f, 0.f, 0.f};

#define GATES(Lidx, hv_)                                            \
  {                                                                 \
    const float* zrow = &zp[Lidx][gch][0];                          \
    float z0 = zrow[gh]       + bias_s[Lidx][gh];                   \
    float z1 = zrow[64 + gh]  + bias_s[Lidx][64 + gh];              \
    float z2 = zrow[128 + gh] + bias_s[Lidx][128 + gh];             \
    float z3 = zrow[192 + gh] + bias_s[Lidx][192 + gh];             \
    float ig = sigm_f(z0), fg = sigm_f(z1);                         \
    float gg = tanh_f(z2), og = sigm_f(z3);                         \
    cst = fg * cst + ig * gg;                                       \
    hv_ = og * tanh_f(cst);                                         \
  }

  // even lane packs (own, neighbor) halves -> one b32 write
#define HSTORE(base_, hv_)                                          \
  {                                                                 \
    _Float16 hf = (_Float16)(hv_);                                  \
    unsigned me = (unsigned)__builtin_bit_cast(unsigned short, hf); \
    unsigned nb = dpp_xor1_u32(me);                                 \
    if ((l & 1) == 0)                                               \
      reinterpret_cast<unsigned*>(base_)[waddr_h >> 1] = me | (nb << 16); \
  }

  __syncthreads();  // hb zeros / bias visible

  for (int t = 0; t <= T_LEN + 1; ++t) {
    // ===== Phase A: L0 MFMA z0(t) -> zp[0] || wv10,11 gates L1(t-2) =====
    if (L == 0) {
      if (t < T_LEN) {
        const _Float16* h0c = &hb[0][(t + 1) & 1][0];  // h0[t-1]
        f16x8 B2 = *reinterpret_cast<const f16x8*>(h0c + rdoff);
        f16x8 B3 = *reinterpret_cast<const f16x8*>(h0c + 64 + rdoff);
        f32x4 a0 = zf4, a1 = zf4;
        a0 = MFMAH(w16[0][0], xb0, a0); a1 = MFMAH(w16[1][0], xb0, a1);
        a0 = MFMAH(w16[0][1], xb1, a0); a1 = MFMAH(w16[1][1], xb1, a1);
        a0 = MFMAH(w16[0][2], B2,  a0); a1 = MFMAH(w16[1][2], B2,  a1);
        a0 = MFMAH(w16[0][3], B3,  a0); a1 = MFMAH(w16[1][3], B3,  a1);
        if (col < NCH) {
          *reinterpret_cast<f32x4*>(&zp[0][col][32 * w8 + 4 * lq])      = a0;
          *reinterpret_cast<f32x4*>(&zp[0][col][32 * w8 + 16 + 4 * lq]) = a1;
        }
      }
    } else if (is_gate) {  // wv10, wv11: gates L1 step t-2
      if (t >= 2) {
        float hv;
        GATES(1, hv)
        if (t == T_LEN + 1) {
          hfin[gch][gh] = hv;
        } else {
          HSTORE(&hb[1][t & 1][0], hv)  // h1[t-2] -> buf (t-2)&1 == t&1
        }
      }
    }

    lds_barrier();

    // ===== Phase B: wv0,1 gates L0(t) || L1 MFMA z1(t-1) -> zp[1] =====
    if (L == 0) {
      if (is_gate && t < T_LEN) {
        float hv;
        GATES(0, hv)
        HSTORE(&hb[0][t & 1][0], hv)    // h0[t]
      }
      // convert x[t+1] (raw regs loaded one iteration ago) -> f16 frags;
      // then issue raw loads for x[t+2] (stay in flight ~1 full iteration)
      if (t + 1 < T_LEN) {
        xbn0 = cvt8(xr0, xr1);
        xbn1 = cvt8(xr2, xr3);
      }
      if (t + 2 < T_LEN) {
        const float* p = xp + (size_t)(t + 2) * H;
        xr0 = *reinterpret_cast<const float4*>(p);
        xr1 = *reinterpret_cast<const float4*>(p + 4);
        xr2 = *reinterpret_cast<const float4*>(p + 32);
        xr3 = *reinterpret_cast<const float4*>(p + 36);
      }
    } else {
      if (t >= 1 && t <= T_LEN) {
        const _Float16* h0c = &hb[0][(t + 1) & 1][0];  // h0[t-1]
        const _Float16* h1c = &hb[1][t & 1][0];        // h1[t-2]
        f16x8 B0 = *reinterpret_cast<const f16x8*>(h0c + rdoff);
        f16x8 B1 = *reinterpret_cast<const f16x8*>(h0c + 64 + rdoff);
        f16x8 B2 = *reinterpret_cast<const f16x8*>(h1c + rdoff);
        f16x8 B3 = *reinterpret_cast<const f16x8*>(h1c + 64 + rdoff);
        f32x4 a0 = zf4, a1 = zf4;
        a0 = MFMAH(w16[0][0], B0, a0); a1 = MFMAH(w16[1][0], B0, a1);
        a0 = MFMAH(w16[0][1], B1, a0); a1 = MFMAH(w16[1][1], B1, a1);
        a0 = MFMAH(w16[0][2], B2, a0); a1 = MFMAH(w16[1][2], B2, a1);
        a0 = MFMAH(w16[0][3], B3, a0); a1 = MFMAH(w16[1][3], B3, a1);
        if (col < NCH) {
          *reinterpret_cast<f32x4*>(&zp[1][col][32 * w8 + 4 * lq])      = a0;
          *reinterpret_cast<f32x4*>(&zp[1][col][32 * w8 + 16 + 4 * lq]) = a1;
        }
      }
    }

    lds_barrier();
    if (L == 0) { xb0 = xbn0; xb1 = xbn1; }
  }
#undef GATES
#undef HSTORE

  // ---- FC epilogue: out = fc_w . h2[T-1] + fc_b ----
  if (tid < NCH) {
    float acc = fc_b[0];
#pragma unroll
    for (int h = 0; h < H; ++h) acc += fcw_s[h] * hfin[tid][h];
    out[blk * NCH + tid] = acc;
  }
}

extern "C" void kernel_launch(void* const* d_in, const int* in_sizes, int n_in,
                              void* d_out, int out_size, void* d_ws, size_t ws_size,
                              hipStream_t stream) {
  const float* x     = (const float*)d_in[0];
  const float* w_ih0 = (const float*)d_in[1];
  const float* w_hh0 = (const float*)d_in[2];
  const float* b_ih0 = (const float*)d_in[3];
  const float* b_hh0 = (const float*)d_in[4];
  const float* w_ih1 = (const float*)d_in[5];
  const float* w_hh1 = (const float*)d_in[6];
  const float* b_ih1 = (const float*)d_in[7];
  const float* b_hh1 = (const float*)d_in[8];
  const float* fc_w  = (const float*)d_in[9];
  const float* fc_b  = (const float*)d_in[10];
  float* out = (float*)d_out;

  lstm_fused<<<dim3(NBLK), dim3(NTHR), 0, stream>>>(
      x, w_ih0, w_hh0, b_ih0, b_hh0, w_ih1, w_hh1, b_ih1, b_hh1,
      fc_w, fc_b, out);
}

// Round 21
// 693.321 us; speedup vs baseline: 1.1965x; 1.1965x over previous
//
#include <hip/hip_runtime.h>
#include <hip/hip_bf16.h>

// LSTMReg on MI355X — round 21: r19 champion restored + T5 s_setprio on MFMA
// clusters. r20 lesson: never add work to the gate waves (critical path);
// prepass restored. r19 residual (~350 cyc/iter over the 1242-cyc per-SIMD
// MFMA-issue floor) is barrier skew + handoff latency + scheduler
// arbitration; r19's per-SIMD role split (3 MFMA waves + 1 gate wave) is
// exactly T5's measured-win regime (+21-39% role-split, 0% lockstep).
// All maps/arithmetic = r19 verbatim -> absmax exactly 2.441406e-4.

typedef _Float16 f16x8 __attribute__((ext_vector_type(8)));
typedef float f32x4  __attribute__((ext_vector_type(4)));

#define MFMAH(A, B, C) __builtin_amdgcn_mfma_f32_16x16x32_f16(A, B, C, 0, 0, 0)

constexpr int T_LEN = 1024;
constexpr int H     = 64;
constexpr int NCH   = 2;     // chains per block -> 256 blocks = all CUs
constexpr int NTHR  = 1024;  // 16 waves = 4/SIMD
constexpr int NBLK  = 256;

// x fragment buffer: [blk][t][kt(2)][lq(4)][ch(2)][8 halfs]
constexpr int    XT_HALFS   = 2 * 4 * 2 * 8;                // 128 halfs per t
constexpr size_t XBLK_HALFS = (size_t)T_LEN * XT_HALFS;     // 256 KiB per block

__device__ __forceinline__ float sigm_f(float x) {
  return __builtin_amdgcn_rcpf(1.0f + __expf(-x));
}
__device__ __forceinline__ float tanh_f(float x) {
  return 1.0f - 2.0f * __builtin_amdgcn_rcpf(1.0f + __expf(2.0f * x));
}
__device__ __forceinline__ unsigned dpp_xor1_u32(unsigned v) {
  return (unsigned)__builtin_amdgcn_mov_dpp((int)v, 0xB1, 0xF, 0xF, true);
}
// LDS-only barrier (keeps global x loads in flight across barriers)
__device__ __forceinline__ void lds_barrier() {
  asm volatile("s_waitcnt lgkmcnt(0)" ::: "memory");
  __builtin_amdgcn_s_barrier();
  asm volatile("" ::: "memory");
}

// ---- pre-pass: x [512][1024][64] fp32 -> fp16 fragment packets ----
__global__ __launch_bounds__(256, 4) void xconv(const float* __restrict__ x,
                                                _Float16* __restrict__ xf) {
  const int gid = blockIdx.x * 256 + threadIdx.x;  // (chain, t, lq)
  const int lq    = gid & 3;
  const int t     = (gid >> 2) & (T_LEN - 1);
  const int chain = gid >> 12;                     // 0..511
  const int ch  = chain & 1;
  const int blk = chain >> 1;
  const float* src = x + ((size_t)chain * T_LEN + t) * H + 8 * lq;
  float4 v0 = *reinterpret_cast<const float4*>(src);
  float4 v1 = *reinterpret_cast<const float4*>(src + 4);
  float4 v2 = *reinterpret_cast<const float4*>(src + 32);
  float4 v3 = *reinterpret_cast<const float4*>(src + 36);
  float a[8]  = {v0.x, v0.y, v0.z, v0.w, v1.x, v1.y, v1.z, v1.w};
  float c8[8] = {v2.x, v2.y, v2.z, v2.w, v3.x, v3.y, v3.z, v3.w};
  f16x8 p0, p1;
#pragma unroll
  for (int e = 0; e < 8; ++e) {
    p0[e] = (_Float16)a[e];
    p1[e] = (_Float16)c8[e];
  }
  _Float16* dst = xf + (size_t)blk * XBLK_HALFS + (size_t)t * XT_HALFS +
                  lq * 16 + ch * 8;
  *reinterpret_cast<f16x8*>(dst)      = p0;  // kt0 (feats 0-31)
  *reinterpret_cast<f16x8*>(dst + 64) = p1;  // kt1 (feats 32-63)
}

__global__ __launch_bounds__(NTHR) void lstm_fused(
    const _Float16* __restrict__ xf,
    const float* __restrict__ w_ih0, const float* __restrict__ w_hh0,
    const float* __restrict__ b_ih0, const float* __restrict__ b_hh0,
    const float* __restrict__ w_ih1, const float* __restrict__ w_hh1,
    const float* __restrict__ b_ih1, const float* __restrict__ b_hh1,
    const float* __restrict__ fc_w, const float* __restrict__ fc_b,
    float* __restrict__ out) {
  const int tid = threadIdx.x;
  const int wv  = tid >> 6;
  const int L   = wv >> 3;   // 0: L0 waves (wv0-7), 1: L1 waves (wv8-15)
  const int w8  = wv & 7;    // row-block: rows [32*w8, 32*w8+32)
  const int l   = tid & 63;
  const int col = l & 15;    // MFMA column; chain = col&1 (8x duplicated)
  const int lq  = l >> 4;
  const int blk = blockIdx.x;

  // h buffers: [layer][buf][kt(2)][lq(4)][ch(2)][e(8)] = 128 halfs per buf
  __shared__ __align__(16) _Float16 hb[2][2][128];
  __shared__ __align__(16) float zp[2][2][260];   // [L][chain][row(+pad)]
  __shared__ float bias_s[2][256];
  __shared__ float fcw_s[H];
  __shared__ float hfin[NCH][H];

  for (int i = tid; i < 2 * 2 * 128; i += NTHR) ((_Float16*)hb)[i] = (_Float16)0.f;
  if (tid < 256)       bias_s[0][tid] = b_ih0[tid] + b_hh0[tid];
  else if (tid < 512)  bias_s[1][tid - 256] = b_ih1[tid - 256] + b_hh1[tid - 256];
  if (tid < H) fcw_s[tid] = fc_w[tid];

  // ---- weights: rows 32*w8 + 16*rt + col; k0 = 32kt + 8lq (= r19 map) ----
  const float* wih = L ? w_ih1 : w_ih0;
  const float* whh = L ? w_hh1 : w_hh0;
  f16x8 w16[2][4];  // [rt][kt] = 32 VGPR
#pragma unroll
  for (int rt = 0; rt < 2; ++rt) {
#pragma unroll
    for (int kt = 0; kt < 4; ++kt) {
      const int row = 32 * w8 + 16 * rt + col;
      const int k0  = 32 * kt + 8 * lq;
      const float* src = (k0 < 64) ? &wih[row * 64 + k0] : &whh[row * 64 + (k0 - 64)];
      float4 v0 = *reinterpret_cast<const float4*>(src);
      float4 v1 = *reinterpret_cast<const float4*>(src + 4);
      float vv[8] = {v0.x, v0.y, v0.z, v0.w, v1.x, v1.y, v1.z, v1.w};
      f16x8 h8;
#pragma unroll
      for (int e = 0; e < 8; ++e) h8[e] = (_Float16)vv[e];
      w16[rt][kt] = h8;
    }
  }

  // B-frag LDS read offset (halfs): lq*16 + (col&1)*8  (+64 for kt1)
  const int rdoff = lq * 16 + (col & 1) * 8;
  // gate waves: wv0(S0),wv1(S1) for L0; wv10(S2),wv11(S3) for L1
  const bool is_gate = (wv < 2) || (wv == 10) || (wv == 11);
  const int gch = wv & 1;    // chain
  const int gh  = l;         // feature
  // h write addr (halfs): f=gh -> kt=gh>>5, lq=(gh>>3)&3, e=gh&7
  const int waddr_h = ((gh >> 5) << 6) + (((gh >> 3) & 3) << 4) + (gch << 3) + (gh & 7);
  float cst = 0.0f;

  // x prefetch (L0 waves)
  const _Float16* xfl = xf + (size_t)blk * XBLK_HALFS + rdoff;
  f16x8 xb0, xb1, xbn0, xbn1;
  if (L == 0) {
    xb0 = *reinterpret_cast<const f16x8*>(xfl);
    xb1 = *reinterpret_cast<const f16x8*>(xfl + 64);
  }

  const f32x4 zf4 = {0.f, 0.f, 0.f, 0.f};

#define GATES(Lidx, hv_)                                            \
  {                                                                 \
    const float* zrow = &zp[Lidx][gch][0];                          \
    float z0 = zrow[gh]       + bias_s[Lidx][gh];                   \
    float z1 = zrow[64 + gh]  + bias_s[Lidx][64 + gh];              \
    float z2 = zrow[128 + gh] + bias_s[Lidx][128 + gh];             \
    float z3 = zrow[192 + gh] + bias_s[Lidx][192 + gh];             \
    float ig = sigm_f(z0), fg = sigm_f(z1);                         \
    float gg = tanh_f(z2), og = sigm_f(z3);                         \
    cst = fg * cst + ig * gg;                                       \
    hv_ = og * tanh_f(cst);                                         \
  }

  // even lane packs (own, neighbor) halves -> one b32 write
#define HSTORE(base_, hv_)                                          \
  {                                                                 \
    _Float16 hf = (_Float16)(hv_);                                  \
    unsigned me = (unsigned)__builtin_bit_cast(unsigned short, hf); \
    unsigned nb = dpp_xor1_u32(me);                                 \
    if ((l & 1) == 0)                                               \
      reinterpret_cast<unsigned*>(base_)[waddr_h >> 1] = me | (nb << 16); \
  }

  __syncthreads();  // hb zeros / bias visible

  for (int t = 0; t <= T_LEN + 1; ++t) {
    // ===== Phase A: L0 MFMA z0(t) -> zp[0] || wv10,11 gates L1(t-2) =====
    if (L == 0) {
      if (t + 1 < T_LEN) {  // issue x[t+1] loads (stay in flight)
        const _Float16* p = xfl + (size_t)(t + 1) * XT_HALFS;
        xbn0 = *reinterpret_cast<const f16x8*>(p);
        xbn1 = *reinterpret_cast<const f16x8*>(p + 64);
      }
      if (t < T_LEN) {
        const _Float16* h0c = &hb[0][(t + 1) & 1][0];  // h0[t-1]
        f16x8 B2 = *reinterpret_cast<const f16x8*>(h0c + rdoff);
        f16x8 B3 = *reinterpret_cast<const f16x8*>(h0c + 64 + rdoff);
        f32x4 a0 = zf4, a1 = zf4;
        __builtin_amdgcn_s_setprio(1);
        a0 = MFMAH(w16[0][0], xb0, a0); a1 = MFMAH(w16[1][0], xb0, a1);
        a0 = MFMAH(w16[0][1], xb1, a0); a1 = MFMAH(w16[1][1], xb1, a1);
        a0 = MFMAH(w16[0][2], B2,  a0); a1 = MFMAH(w16[1][2], B2,  a1);
        a0 = MFMAH(w16[0][3], B3,  a0); a1 = MFMAH(w16[1][3], B3,  a1);
        __builtin_amdgcn_s_setprio(0);
        if (col < NCH) {
          *reinterpret_cast<f32x4*>(&zp[0][col][32 * w8 + 4 * lq])      = a0;
          *reinterpret_cast<f32x4*>(&zp[0][col][32 * w8 + 16 + 4 * lq]) = a1;
        }
      }
    } else if (is_gate) {  // wv10, wv11: gates L1 step t-2
      if (t >= 2) {
        float hv;
        GATES(1, hv)
        if (t == T_LEN + 1) {
          hfin[gch][gh] = hv;
        } else {
          HSTORE(&hb[1][t & 1][0], hv)  // h1[t-2] -> buf (t-2)&1 == t&1
        }
      }
    }

    lds_barrier();

    // ===== Phase B: wv0,1 gates L0(t) || L1 MFMA z1(t-1) -> zp[1] =====
    if (L == 0) {
      if (is_gate && t < T_LEN) {
        float hv;
        GATES(0, hv)
        HSTORE(&hb[0][t & 1][0], hv)    // h0[t]
      }
    } else {
      if (t >= 1 && t <= T_LEN) {
        const _Float16* h0c = &hb[0][(t + 1) & 1][0];  // h0[t-1]
        const _Float16* h1c = &hb[1][t & 1][0];        // h1[t-2]
        f16x8 B0 = *reinterpret_cast<const f16x8*>(h0c + rdoff);
        f16x8 B1 = *reinterpret_cast<const f16x8*>(h0c + 64 + rdoff);
        f16x8 B2 = *reinterpret_cast<const f16x8*>(h1c + rdoff);
        f16x8 B3 = *reinterpret_cast<const f16x8*>(h1c + 64 + rdoff);
        f32x4 a0 = zf4, a1 = zf4;
        __builtin_amdgcn_s_setprio(1);
        a0 = MFMAH(w16[0][0], B0, a0); a1 = MFMAH(w16[1][0], B0, a1);
        a0 = MFMAH(w16[0][1], B1, a0); a1 = MFMAH(w16[1][1], B1, a1);
        a0 = MFMAH(w16[0][2], B2, a0); a1 = MFMAH(w16[1][2], B2, a1);
        a0 = MFMAH(w16[0][3], B3, a0); a1 = MFMAH(w16[1][3], B3, a1);
        __builtin_amdgcn_s_setprio(0);
        if (col < NCH) {
          *reinterpret_cast<f32x4*>(&zp[1][col][32 * w8 + 4 * lq])      = a0;
          *reinterpret_cast<f32x4*>(&zp[1][col][32 * w8 + 16 + 4 * lq]) = a1;
        }
      }
    }

    lds_barrier();
    if (L == 0) { xb0 = xbn0; xb1 = xbn1; }
  }
#undef GATES
#undef HSTORE

  // ---- FC epilogue: out = fc_w . h2[T-1] + fc_b ----
  if (tid < NCH) {
    float acc = fc_b[0];
#pragma unroll
    for (int h = 0; h < H; ++h) acc += fcw_s[h] * hfin[tid][h];
    out[blk * NCH + tid] = acc;
  }
}

extern "C" void kernel_launch(void* const* d_in, const int* in_sizes, int n_in,
                              void* d_out, int out_size, void* d_ws, size_t ws_size,
                              hipStream_t stream) {
  const float* x     = (const float*)d_in[0];
  const float* w_ih0 = (const float*)d_in[1];
  const float* w_hh0 = (const float*)d_in[2];
  const float* b_ih0 = (const float*)d_in[3];
  const float* b_hh0 = (const float*)d_in[4];
  const float* w_ih1 = (const float*)d_in[5];
  const float* w_hh1 = (const float*)d_in[6];
  const float* b_ih1 = (const float*)d_in[7];
  const float* b_hh1 = (const float*)d_in[8];
  const float* fc_w  = (const float*)d_in[9];
  const float* fc_b  = (const float*)d_in[10];
  float* out = (float*)d_out;

  _Float16* xfrag = (_Float16*)d_ws;  // 64 MiB used

  xconv<<<dim3(8192), dim3(256), 0, stream>>>(x, xfrag);
  lstm_fused<<<dim3(NBLK), dim3(NTHR), 0, stream>>>(
      xfrag, w_ih0, w_hh0, b_ih0, b_hh0, w_ih1, w_hh1, b_ih1, b_hh1,
      fc_w, fc_b, out);
}

// Round 22
// 667.925 us; speedup vs baseline: 1.2420x; 1.0380x over previous
//
#include <hip/hip_runtime.h>
#include <hip/hip_bf16.h>

// LSTMReg on MI355X — round 22: r21 + IN-KERNEL x CONVERSION ON wv2 ONLY.
// r21 (693us) = ~38us serialized xconv prepass + fused loop. r20's fused
// conversion failed because it loaded the critical-path GATE waves (wv0/1).
// Fix: wave wv2 (non-gate L0, idle in phase B) owns the whole x pipeline:
// loads raw fp32 one iteration ahead (~1600cyc in flight), converts (RNE,
// bit-identical to xconv) and ds_writes fp16 packets to a double-buffered
// 512B xstage in phase B; all L0 waves ds_read x-frags in phase A (latency
// shared with h-reads). Gate waves untouched. Prepass + workspace deleted.
// Maps/schedule/setprio = r21 verbatim -> absmax exactly 2.441406e-4.

typedef _Float16 f16x8 __attribute__((ext_vector_type(8)));
typedef float f32x4  __attribute__((ext_vector_type(4)));

#define MFMAH(A, B, C) __builtin_amdgcn_mfma_f32_16x16x32_f16(A, B, C, 0, 0, 0)

constexpr int T_LEN = 1024;
constexpr int H     = 64;
constexpr int NCH   = 2;     // chains per block -> 256 blocks = all CUs
constexpr int NTHR  = 1024;  // 16 waves = 4/SIMD
constexpr int NBLK  = 256;

__device__ __forceinline__ float sigm_f(float x) {
  return __builtin_amdgcn_rcpf(1.0f + __expf(-x));
}
__device__ __forceinline__ float tanh_f(float x) {
  return 1.0f - 2.0f * __builtin_amdgcn_rcpf(1.0f + __expf(2.0f * x));
}
__device__ __forceinline__ unsigned dpp_xor1_u32(unsigned v) {
  return (unsigned)__builtin_amdgcn_mov_dpp((int)v, 0xB1, 0xF, 0xF, true);
}
// LDS-only barrier (keeps global x loads in flight across barriers)
__device__ __forceinline__ void lds_barrier() {
  asm volatile("s_waitcnt lgkmcnt(0)" ::: "memory");
  __builtin_amdgcn_s_barrier();
  asm volatile("" ::: "memory");
}
__device__ __forceinline__ unsigned pack2_f16(float a, float b) {
  unsigned u0 = (unsigned)__builtin_bit_cast(unsigned short, (_Float16)a);
  unsigned u1 = (unsigned)__builtin_bit_cast(unsigned short, (_Float16)b);
  return u0 | (u1 << 16);
}

__global__ __launch_bounds__(NTHR) void lstm_fused(
    const float* __restrict__ xin,
    const float* __restrict__ w_ih0, const float* __restrict__ w_hh0,
    const float* __restrict__ b_ih0, const float* __restrict__ b_hh0,
    const float* __restrict__ w_ih1, const float* __restrict__ w_hh1,
    const float* __restrict__ b_ih1, const float* __restrict__ b_hh1,
    const float* __restrict__ fc_w, const float* __restrict__ fc_b,
    float* __restrict__ out) {
  const int tid = threadIdx.x;
  const int wv  = tid >> 6;
  const int L   = wv >> 3;   // 0: L0 waves (wv0-7), 1: L1 waves (wv8-15)
  const int w8  = wv & 7;    // row-block: rows [32*w8, 32*w8+32)
  const int l   = tid & 63;
  const int col = l & 15;    // MFMA column; chain = col&1 (8x duplicated)
  const int lq  = l >> 4;
  const int blk = blockIdx.x;

  // h buffers: [layer][buf][kt(2)][lq(4)][ch(2)][e(8)] = 128 halfs per buf
  __shared__ __align__(16) _Float16 hb[2][2][128];
  // x staging, same packet layout, double-buffered (wv2-produced)
  __shared__ __align__(16) _Float16 xstage[2][128];
  __shared__ __align__(16) float zp[2][2][260];   // [L][chain][row(+pad)]
  __shared__ float bias_s[2][256];
  __shared__ float fcw_s[H];
  __shared__ float hfin[NCH][H];

  for (int i = tid; i < 2 * 2 * 128; i += NTHR) ((_Float16*)hb)[i] = (_Float16)0.f;
  if (tid < 256)       bias_s[0][tid] = b_ih0[tid] + b_hh0[tid];
  else if (tid < 512)  bias_s[1][tid - 256] = b_ih1[tid - 256] + b_hh1[tid - 256];
  if (tid < H) fcw_s[tid] = fc_w[tid];

  // ---- weights: rows 32*w8 + 16*rt + col; k0 = 32kt + 8lq (= r21 map) ----
  const float* wih = L ? w_ih1 : w_ih0;
  const float* whh = L ? w_hh1 : w_hh0;
  f16x8 w16[2][4];  // [rt][kt] = 32 VGPR
#pragma unroll
  for (int rt = 0; rt < 2; ++rt) {
#pragma unroll
    for (int kt = 0; kt < 4; ++kt) {
      const int row = 32 * w8 + 16 * rt + col;
      const int k0  = 32 * kt + 8 * lq;
      const float* src = (k0 < 64) ? &wih[row * 64 + k0] : &whh[row * 64 + (k0 - 64)];
      float4 v0 = *reinterpret_cast<const float4*>(src);
      float4 v1 = *reinterpret_cast<const float4*>(src + 4);
      float vv[8] = {v0.x, v0.y, v0.z, v0.w, v1.x, v1.y, v1.z, v1.w};
      f16x8 h8;
#pragma unroll
      for (int e = 0; e < 8; ++e) h8[e] = (_Float16)vv[e];
      w16[rt][kt] = h8;
    }
  }

  // B-frag LDS read offset (halfs): lq*16 + (col&1)*8  (+64 for kt1)
  const int rdoff = lq * 16 + (col & 1) * 8;
  // gate waves: wv0(S0),wv1(S1) for L0; wv10(S2),wv11(S3) for L1
  const bool is_gate = (wv < 2) || (wv == 10) || (wv == 11);
  const int gch = wv & 1;    // chain
  const int gh  = l;         // feature
  // h write addr (halfs): f=gh -> kt=gh>>5, lq=(gh>>3)&3, e=gh&7
  const int waddr_h = ((gh >> 5) << 6) + (((gh >> 3) & 3) << 4) + (gch << 3) + (gh & 7);
  float cst = 0.0f;

  // ---- x stager (wave wv2 only): lane l owns packed word l of a packet ----
  // word l covers halfs {2l, 2l+1}: kt=l>>5, lq=(l>>3)&3, ch=(l>>2)&1,
  // e0=2*(l&3); feature f = kt*32 + lq*8 + e0. Layout == old xconv packet.
  const bool is_stager = (L == 0) && (w8 == 2);
  const int skt = l >> 5, slq = (l >> 3) & 3, sch = (l >> 2) & 1;
  const int sf  = skt * 32 + slq * 8 + 2 * (l & 3);
  const float* xsp = xin + ((size_t)(blk * NCH + sch) * T_LEN) * H + sf;
  float xrA = 0.f, xrB = 0.f;  // raw fp32 for step t+1 (one iteration in flight)
  if (is_stager) {
    float2 v0 = *reinterpret_cast<const float2*>(xsp);       // t = 0
    reinterpret_cast<unsigned*>(&xstage[0][0])[l] = pack2_f16(v0.x, v0.y);
    float2 v1 = *reinterpret_cast<const float2*>(xsp + H);   // t = 1 (in flight)
    xrA = v1.x; xrB = v1.y;
  }

  const f32x4 zf4 = {0.f, 0.f, 0.f, 0.f};

#define GATES(Lidx, hv_)                                            \
  {                                                                 \
    const float* zrow = &zp[Lidx][gch][0];                          \
    float z0 = zrow[gh]       + bias_s[Lidx][gh];                   \
    float z1 = zrow[64 + gh]  + bias_s[Lidx][64 + gh];              \
    float z2 = zrow[128 + gh] + bias_s[Lidx][128 + gh];             \
    float z3 = zrow[192 + gh] + bias_s[Lidx][192 + gh];             \
    float ig = sigm_f(z0), fg = sigm_f(z1);                         \
    float gg = tanh_f(z2), og = sigm_f(z3);                         \
    cst = fg * cst + ig * gg;                                       \
    hv_ = og * tanh_f(cst);                                         \
  }

  // even lane packs (own, neighbor) halves -> one b32 write
#define HSTORE(base_, hv_)                                          \
  {                                                                 \
    _Float16 hf = (_Float16)(hv_);                                  \
    unsigned me = (unsigned)__builtin_bit_cast(unsigned short, hf); \
    unsigned nb = dpp_xor1_u32(me);                                 \
    if ((l & 1) == 0)                                               \
      reinterpret_cast<unsigned*>(base_)[waddr_h >> 1] = me | (nb << 16); \
  }

  __syncthreads();  // hb zeros / bias / xstage[0] visible

  for (int t = 0; t <= T_LEN + 1; ++t) {
    // ===== Phase A: L0 MFMA z0(t) -> zp[0] || wv10,11 gates L1(t-2) =====
    if (L == 0) {
      if (t < T_LEN) {
        const _Float16* h0c = &hb[0][(t + 1) & 1][0];  // h0[t-1]
        const _Float16* xs  = &xstage[t & 1][0];       // x[t] packets
        f16x8 xb0 = *reinterpret_cast<const f16x8*>(xs + rdoff);
        f16x8 xb1 = *reinterpret_cast<const f16x8*>(xs + 64 + rdoff);
        f16x8 B2 = *reinterpret_cast<const f16x8*>(h0c + rdoff);
        f16x8 B3 = *reinterpret_cast<const f16x8*>(h0c + 64 + rdoff);
        f32x4 a0 = zf4, a1 = zf4;
        __builtin_amdgcn_s_setprio(1);
        a0 = MFMAH(w16[0][0], xb0, a0); a1 = MFMAH(w16[1][0], xb0, a1);
        a0 = MFMAH(w16[0][1], xb1, a0); a1 = MFMAH(w16[1][1], xb1, a1);
        a0 = MFMAH(w16[0][2], B2,  a0); a1 = MFMAH(w16[1][2], B2,  a1);
        a0 = MFMAH(w16[0][3], B3,  a0); a1 = MFMAH(w16[1][3], B3,  a1);
        __builtin_amdgcn_s_setprio(0);
        if (col < NCH) {
          *reinterpret_cast<f32x4*>(&zp[0][col][32 * w8 + 4 * lq])      = a0;
          *reinterpret_cast<f32x4*>(&zp[0][col][32 * w8 + 16 + 4 * lq]) = a1;
        }
      }
    } else if (is_gate) {  // wv10, wv11: gates L1 step t-2
      if (t >= 2) {
        float hv;
        GATES(1, hv)
        if (t == T_LEN + 1) {
          hfin[gch][gh] = hv;
        } else {
          HSTORE(&hb[1][t & 1][0], hv)  // h1[t-2] -> buf (t-2)&1 == t&1
        }
      }
    }

    lds_barrier();

    // ===== Phase B: wv0,1 gates L0(t) || L1 MFMA z1(t-1) -> zp[1] =====
    if (L == 0) {
      if (is_gate && t < T_LEN) {
        float hv;
        GATES(0, hv)
        HSTORE(&hb[0][t & 1][0], hv)    // h0[t]
      }
      if (is_stager) {
        if (t + 1 < T_LEN)  // convert x[t+1] (raw, 1 iter in flight) -> stage
          reinterpret_cast<unsigned*>(&xstage[(t + 1) & 1][0])[l] =
              pack2_f16(xrA, xrB);
        if (t + 2 < T_LEN) {  // issue raw loads for x[t+2]
          float2 v = *reinterpret_cast<const float2*>(xsp + (size_t)(t + 2) * H);
          xrA = v.x; xrB = v.y;
        }
      }
    } else {
      if (t >= 1 && t <= T_LEN) {
        const _Float16* h0c = &hb[0][(t + 1) & 1][0];  // h0[t-1]
        const _Float16* h1c = &hb[1][t & 1][0];        // h1[t-2]
        f16x8 B0 = *reinterpret_cast<const f16x8*>(h0c + rdoff);
        f16x8 B1 = *reinterpret_cast<const f16x8*>(h0c + 64 + rdoff);
        f16x8 B2 = *reinterpret_cast<const f16x8*>(h1c + rdoff);
        f16x8 B3 = *reinterpret_cast<const f16x8*>(h1c + 64 + rdoff);
        f32x4 a0 = zf4, a1 = zf4;
        __builtin_amdgcn_s_setprio(1);
        a0 = MFMAH(w16[0][0], B0, a0); a1 = MFMAH(w16[1][0], B0, a1);
        a0 = MFMAH(w16[0][1], B1, a0); a1 = MFMAH(w16[1][1], B1, a1);
        a0 = MFMAH(w16[0][2], B2, a0); a1 = MFMAH(w16[1][2], B2, a1);
        a0 = MFMAH(w16[0][3], B3, a0); a1 = MFMAH(w16[1][3], B3, a1);
        __builtin_amdgcn_s_setprio(0);
        if (col < NCH) {
          *reinterpret_cast<f32x4*>(&zp[1][col][32 * w8 + 4 * lq])      = a0;
          *reinterpret_cast<f32x4*>(&zp[1][col][32 * w8 + 16 + 4 * lq]) = a1;
        }
      }
    }

    lds_barrier();
  }
#undef GATES
#undef HSTORE

  // ---- FC epilogue: out = fc_w . h2[T-1] + fc_b ----
  if (tid < NCH) {
    float acc = fc_b[0];
#pragma unroll
    for (int h = 0; h < H; ++h) acc += fcw_s[h] * hfin[tid][h];
    out[blk * NCH + tid] = acc;
  }
}

extern "C" void kernel_launch(void* const* d_in, const int* in_sizes, int n_in,
                              void* d_out, int out_size, void* d_ws, size_t ws_size,
                              hipStream_t stream) {
  const float* x     = (const float*)d_in[0];
  const float* w_ih0 = (const float*)d_in[1];
  const float* w_hh0 = (const float*)d_in[2];
  const float* b_ih0 = (const float*)d_in[3];
  const float* b_hh0 = (const float*)d_in[4];
  const float* w_ih1 = (const float*)d_in[5];
  const float* w_hh1 = (const float*)d_in[6];
  const float* b_ih1 = (const float*)d_in[7];
  const float* b_hh1 = (const float*)d_in[8];
  const float* fc_w  = (const float*)d_in[9];
  const float* fc_b  = (const float*)d_in[10];
  float* out = (float*)d_out;

  lstm_fused<<<dim3(NBLK), dim3(NTHR), 0, stream>>>(
      x, w_ih0, w_hh0, b_ih0, b_hh0, w_ih1, w_hh1, b_ih1, b_hh1,
      fc_w, fc_b, out);
}